// Round 1
// baseline (114.760 us; speedup 1.0000x reference)
//
#include <hip/hip_runtime.h>
#include <hip/hip_bf16.h>

#define NMOD 64
#define INPD 256
#define OUTD 256
#define BATCH 2048
#define TT 64

typedef __attribute__((ext_vector_type(8))) short short8;
typedef __attribute__((ext_vector_type(4))) float floatx4;

__device__ __forceinline__ unsigned int pack2(float a, float b) {
    union { float f; unsigned int u; } ua, ub; ua.f = a; ub.f = b;
    unsigned int ra = ua.u + 0x7fffu + ((ua.u >> 16) & 1u);
    unsigned int rb = ub.u + 0x7fffu + ((ub.u >> 16) & 1u);
    return (ra >> 16) | (rb & 0xffff0000u);
}

// Repack W [e][n][k] f32 -> fragment-major bf16:
//   Wpack elem index = (((e*8 + ks)*16 + frag)*64 + lane)*8 + j
//   frag = w*4 + ni  (wave w owns cols w*64..w*64+63; ni = 16-col group)
//   source n = (frag>>3)*128 + (frag&7)*16 + (lane&15)
//   source k = ks*32 + (lane>>4)*8 + j
// GEMM B-loads then become lane-contiguous 1024B bursts.
__global__ __launch_bounds__(256) void conv_w_kernel(const float* __restrict__ W,
                                                     uint4* __restrict__ Wp) {
    int gid  = blockIdx.x * 256 + threadIdx.x;   // 0 .. 524287 (one 8-elem frag slice)
    int lane = gid & 63;
    int frag = (gid >> 6) & 15;
    int ks   = (gid >> 10) & 7;
    int e    = gid >> 13;

    int n = (frag >> 3) * 128 + (frag & 7) * 16 + (lane & 15);
    int k = ks * 32 + (lane >> 4) * 8;

    const float* p = W + ((size_t)e * OUTD + n) * INPD + k;
    float4 v0 = *reinterpret_cast<const float4*>(p);
    float4 v1 = *reinterpret_cast<const float4*>(p + 4);
    Wp[gid] = make_uint4(pack2(v0.x, v0.y), pack2(v0.z, v0.w),
                         pack2(v1.x, v1.y), pack2(v1.z, v1.w));
}

// One block per sample, 4 waves; wave w owns output cols [w*64, w*64+64).
// NO LDS, NO barrier: A fragments loaded straight from global f32 (fully
// coalesced: lane quads cover 16 rows x 128 contiguous bytes per fragment),
// converted to bf16 in-register. The 4x per-block A re-read hits L1/L2 (the
// 4 waves walk the same 8KB/iter window); HBM first-touch stays 1x.
// MFMA operands are SWAPPED (W as A-op, x as B-op) so D[o][t] gives each
// lane 4 consecutive output cols -> float4 stores + float4 bias loads.
template <bool PRECONV>
__global__ __launch_bounds__(256, 4) void moe_gemm_kernel(
    const float* __restrict__ x, const int* __restrict__ idx,
    const void* __restrict__ Wsrc, const float* __restrict__ bias,
    float* __restrict__ y) {

    const int b    = blockIdx.x;
    const int tid  = threadIdx.x;
    const int lane = tid & 63;
    const int w    = tid >> 6;
    const int e    = idx[b];
    const int l15  = lane & 15;
    const int kq   = lane >> 4;

    // Per-lane A base: row t = mi*16 + l15, col base kq*8 (+ ks*32 per step)
    const float* xa = x + (size_t)b * (TT * INPD) + (size_t)l15 * INPD + kq * 8;

    const unsigned short* wp0 = nullptr;
    const float* Wf = nullptr;
    if (PRECONV) {
        // elem = (e*8+ks)*8192 + (w*4+ni)*512 + lane*8
        wp0 = reinterpret_cast<const unsigned short*>(Wsrc)
              + ((size_t)e << 16) + (w << 11) + (lane << 3);
    } else {
        Wf = reinterpret_cast<const float*>(Wsrc) + (size_t)e * OUTD * INPD;
    }

    floatx4 acc[4][4] = {};

#pragma unroll
    for (int ks = 0; ks < 8; ++ks) {
        // A fragments: lane holds x[t = mi*16 + l15][k = ks*32 + kq*8 .. +7]
        short8 af[4];
#pragma unroll
        for (int mi = 0; mi < 4; ++mi) {
            const float* p = xa + mi * (16 * INPD) + ks * 32;
            float4 v0 = *reinterpret_cast<const float4*>(p);
            float4 v1 = *reinterpret_cast<const float4*>(p + 4);
            union { short8 s; uint4 u; } cv;
            cv.u = make_uint4(pack2(v0.x, v0.y), pack2(v0.z, v0.w),
                              pack2(v1.x, v1.y), pack2(v1.z, v1.w));
            af[mi] = cv.s;
        }
        // B fragments: lane holds W[n = w*64 + ni*16 + l15][k = ks*32 + kq*8 .. +7]
        short8 bf[4];
        if (PRECONV) {
            const unsigned short* wp = wp0 + ((size_t)ks << 13);
#pragma unroll
            for (int ni = 0; ni < 4; ++ni)
                bf[ni] = *reinterpret_cast<const short8*>(wp + (ni << 9));
        } else {
#pragma unroll
            for (int ni = 0; ni < 4; ++ni) {
                int n = w * 64 + ni * 16 + l15;
                int k = ks * 32 + kq * 8;
                const float* p = Wf + (size_t)n * INPD + k;
                float4 v0 = *reinterpret_cast<const float4*>(p);
                float4 v1 = *reinterpret_cast<const float4*>(p + 4);
                union { short8 s; uint4 u; } cv;
                cv.u = make_uint4(pack2(v0.x, v0.y), pack2(v0.z, v0.w),
                                  pack2(v1.x, v1.y), pack2(v1.z, v1.w));
                bf[ni] = cv.s;
            }
        }
        // Swapped operands: D[m=o][n=t] = sum_k W[o][k] * x[t][k]
#pragma unroll
        for (int mi = 0; mi < 4; ++mi)
#pragma unroll
            for (int ni = 0; ni < 4; ++ni)
                acc[mi][ni] = __builtin_amdgcn_mfma_f32_16x16x32_bf16(
                    bf[ni], af[mi], acc[mi][ni], 0, 0, 0);
    }

    // Epilogue. D layout (swapped): col = lane&15 -> token within mi-group,
    // row = kq*4 + r -> output col within ni-group => lane holds 4 consecutive
    // output cols for one token: float4 store, float4 bias.
    const floatx4* bp = reinterpret_cast<const floatx4*>(bias + e * OUTD + w * 64) + kq;
    floatx4 bv[4];
#pragma unroll
    for (int ni = 0; ni < 4; ++ni)
        bv[ni] = bp[ni * 4];

    float* yb = y + (size_t)b * (TT * OUTD) + (size_t)l15 * OUTD + w * 64 + kq * 4;
#pragma unroll
    for (int mi = 0; mi < 4; ++mi) {
        float* yrow = yb + mi * (16 * OUTD);
#pragma unroll
        for (int ni = 0; ni < 4; ++ni)
            *reinterpret_cast<floatx4*>(yrow + ni * 16) = acc[mi][ni] + bv[ni];
    }
}

extern "C" void kernel_launch(void* const* d_in, const int* in_sizes, int n_in,
                              void* d_out, int out_size, void* d_ws, size_t ws_size,
                              hipStream_t stream) {
    const float* x    = (const float*)d_in[0];   // [2048, 64, 256] f32
    const int*   idx  = (const int*)d_in[1];     // [2048] i32
    const float* W    = (const float*)d_in[2];   // [64, 256, 256] f32
    const float* bias = (const float*)d_in[3];   // [64, 256] f32
    float*       y    = (float*)d_out;           // [2048, 64, 256] f32

    const size_t w_elems      = (size_t)NMOD * OUTD * INPD;          // 4,194,304
    const size_t w_bf16_bytes = w_elems * sizeof(unsigned short);    // 8 MiB

    if (ws_size >= w_bf16_bytes) {
        conv_w_kernel<<<(unsigned)(w_elems / 8 / 256), 256, 0, stream>>>(
            W, reinterpret_cast<uint4*>(d_ws));
        moe_gemm_kernel<true><<<BATCH, 256, 0, stream>>>(x, idx, d_ws, bias, y);
    } else {
        moe_gemm_kernel<false><<<BATCH, 256, 0, stream>>>(x, idx, (const void*)W, bias, y);
    }
}